// Round 1
// 17471.353 us; speedup vs baseline: 1.4158x; 1.4158x over previous
//
#include <hip/hip_runtime.h>

// All tensors fp32 (per the reference: inputs, weights, outputs all float32).

// ---------------------------------------------------------------------------
// Direct conv1d. Each thread: 4 output channels at one t. Optional fused
// input-side GN+ReLU (scale/shift per (b_local,cin)), residual add, out relu.
// ---------------------------------------------------------------------------
template<int K>
__global__ __launch_bounds__(256) void conv1d_k(
    const float* __restrict__ in, const float* __restrict__ w,
    const float* __restrict__ bias, float* __restrict__ out,
    const float* __restrict__ scale, const float* __restrict__ shift,
    const float* __restrict__ resid,
    int Cin, int Lin, int Lout, int stride, int pad,
    int relu_out, int Cout)
{
    int t = blockIdx.x * 256 + threadIdx.x;
    if (t >= Lout) return;
    int o0 = blockIdx.y * 4;
    int b  = blockIdx.z;

    float acc[4];
    #pragma unroll
    for (int c = 0; c < 4; ++c) acc[c] = bias ? bias[o0 + c] : 0.0f;

    const float* inb = in + (size_t)b * Cin * Lin;
    const float* wb = w + (size_t)o0 * Cin * K;
    const size_t wstride = (size_t)Cin * K;

    int p0 = t * stride - pad;
    bool fast = (p0 >= 0) && (p0 + K <= Lin);

    for (int i = 0; i < Cin; ++i) {
        const float* xi = inb + (size_t)i * Lin;
        float sc = 0.f, sh = 0.f;
        if (scale) { sc = scale[b * Cin + i]; sh = shift[b * Cin + i]; }
        if (fast) {
            #pragma unroll
            for (int k = 0; k < K; ++k) {
                float v = xi[p0 + k];
                if (scale) v = fmaxf(v * sc + sh, 0.0f);
                #pragma unroll
                for (int c = 0; c < 4; ++c)
                    acc[c] += v * wb[c * wstride + i * K + k];
            }
        } else {
            #pragma unroll
            for (int k = 0; k < K; ++k) {
                int p = p0 + k;
                if (p >= 0 && p < Lin) {
                    float v = xi[p];
                    if (scale) v = fmaxf(v * sc + sh, 0.0f);
                    #pragma unroll
                    for (int c = 0; c < 4; ++c)
                        acc[c] += v * wb[c * wstride + i * K + k];
                }
            }
        }
    }
    if (resid) {
        size_t r0 = ((size_t)b * Cout + o0) * Lout + t;
        #pragma unroll
        for (int c = 0; c < 4; ++c) acc[c] += resid[r0 + (size_t)c * Lout];
    }
    if (relu_out) {
        #pragma unroll
        for (int c = 0; c < 4; ++c) acc[c] = fmaxf(acc[c], 0.f);
    }
    size_t i0 = ((size_t)b * Cout + o0) * Lout + t;
    #pragma unroll
    for (int c = 0; c < 4; ++c) out[i0 + (size_t)c * Lout] = acc[c];
}

// ---------------------------------------------------------------------------
// ConvTranspose1d stride-2, parity-split form. One thread owns input index
// t2 and produces output positions 2*t2 and 2*t2+1 for 8 output channels.
//   d1: K=3, pad_lo=1:  out[2t]   = w[1]*in[t]
//                        out[2t+1] = w[0]*in[t] + w[2]*in[t+1]
//   d2: K=5, pad_lo=2:  out[2t]   = w[0]*in[t-1] + w[2]*in[t] + w[4]*in[t+1]
//                        out[2t+1] = w[1]*in[t]   + w[3]*in[t+1]
// Weights are wave-uniform -> scalar loads; inputs plain coalesced dwords;
// no parity divergence; float2 coalesced stores. Fused ReLU.
// ---------------------------------------------------------------------------
template<int K>
__global__ __launch_bounds__(256) void convt2_k(
    const float* __restrict__ in, const float* __restrict__ w,
    const float* __restrict__ bias, float* __restrict__ out,
    int Cin, int Lin, int Cout)
{
    int t2 = blockIdx.x * 256 + threadIdx.x;
    if (t2 >= Lin) return;
    int o0 = blockIdx.y * 8;
    int b  = blockIdx.z;
    const int Lout = 2 * Lin;

    const float* inb = in + (size_t)b * Cin * Lin;
    const float* wb  = w + (size_t)o0 * Cin * K;
    const size_t ws  = (size_t)Cin * K;

    float accE[8], accO[8];
    #pragma unroll
    for (int c = 0; c < 8; ++c) { float bv = bias[o0 + c]; accE[c] = bv; accO[c] = bv; }

    const bool hasp = (t2 + 1 < Lin);
    const bool hasm = (t2 - 1 >= 0);
    const bool interior = (K == 3) ? hasp : (hasp && hasm);

    if (interior) {
        for (int i = 0; i < Cin; ++i) {
            const float* xi = inb + (size_t)i * Lin;
            float v0 = xi[t2];
            float vp = xi[t2 + 1];
            float vm;
            if constexpr (K == 5) vm = xi[t2 - 1];
            const float* wi = wb + (size_t)i * K;
            #pragma unroll
            for (int c = 0; c < 8; ++c) {
                const float* wc = wi + (size_t)c * ws;
                if constexpr (K == 3) {
                    accE[c] += wc[1] * v0;
                    accO[c] += wc[0] * v0 + wc[2] * vp;
                } else {
                    accE[c] += wc[0] * vm + wc[2] * v0 + wc[4] * vp;
                    accO[c] += wc[1] * v0 + wc[3] * vp;
                }
            }
        }
    } else {
        for (int i = 0; i < Cin; ++i) {
            const float* xi = inb + (size_t)i * Lin;
            float v0 = xi[t2];
            float vp = hasp ? xi[t2 + 1] : 0.f;
            float vm = 0.f;
            if constexpr (K == 5) { if (hasm) vm = xi[t2 - 1]; }
            const float* wi = wb + (size_t)i * K;
            #pragma unroll
            for (int c = 0; c < 8; ++c) {
                const float* wc = wi + (size_t)c * ws;
                if constexpr (K == 3) {
                    accE[c] += wc[1] * v0;
                    accO[c] += wc[0] * v0 + wc[2] * vp;
                } else {
                    accE[c] += wc[0] * vm + wc[2] * v0 + wc[4] * vp;
                    accO[c] += wc[1] * v0 + wc[3] * vp;
                }
            }
        }
    }

    size_t base = ((size_t)b * Cout + o0) * (size_t)Lout + (size_t)(2 * t2);
    #pragma unroll
    for (int c = 0; c < 8; ++c) {
        float2 v;
        v.x = fmaxf(accE[c], 0.f);
        v.y = fmaxf(accO[c], 0.f);
        *(float2*)(out + base + (size_t)c * Lout) = v;
    }
}

// ---------------------------------------------------------------------------
// GroupNorm stats -> per-(b_local,c) scale/shift (eps 1e-5)
// ---------------------------------------------------------------------------
__global__ __launch_bounds__(256) void gnstats_k(
    const float* __restrict__ x, const float* __restrict__ g,
    const float* __restrict__ be, float* __restrict__ scale,
    float* __restrict__ shift, int C, int L, int G)
{
    int tid = threadIdx.x;
    int b = blockIdx.x / G, gr = blockIdx.x % G;
    int cpg = C / G;
    size_t n = (size_t)cpg * L;
    const float* base = x + ((size_t)b * C + (size_t)gr * cpg) * L;
    float s = 0.f, s2 = 0.f;
    for (size_t idx = tid; idx < n; idx += 256) { float v = base[idx]; s += v; s2 += v * v; }
    __shared__ float rs[256], rq[256];
    rs[tid] = s; rq[tid] = s2; __syncthreads();
    for (int off = 128; off > 0; off >>= 1) {
        if (tid < off) { rs[tid] += rs[tid + off]; rq[tid] += rq[tid + off]; }
        __syncthreads();
    }
    float mean = rs[0] / (float)n;
    float var  = rq[0] / (float)n - mean * mean;
    float inv  = rsqrtf(var + 1e-5f);
    if (tid < cpg) {
        int c = gr * cpg + tid;
        float ga = g[c], bb = be[c];
        scale[b * C + c] = inv * ga;
        shift[b * C + c] = bb - mean * inv * ga;
    }
}

// ---------------------------------------------------------------------------
// pre-VQ 1x1 conv on one batch-quarter (8 samples); writes z [pos,128] fp32.
// ---------------------------------------------------------------------------
__global__ __launch_bounds__(256) void prevq_k(
    const float* __restrict__ h3q, const float* __restrict__ w,
    const float* __restrict__ bias, float* __restrict__ zq)
{
    int t = blockIdx.x * 256 + threadIdx.x;   // < 1024
    int o0 = blockIdx.y * 4;                  // < 128
    int b  = blockIdx.z;                      // < 8 (local)

    float acc[4];
    #pragma unroll
    for (int c = 0; c < 4; ++c) acc[c] = bias[o0 + c];
    const float* inb = h3q + (size_t)b * 512 * 1024;
    for (int i = 0; i < 512; ++i) {
        float v = inb[(size_t)i * 1024 + t];
        #pragma unroll
        for (int c = 0; c < 4; ++c) acc[c] += v * w[(size_t)(o0 + c) * 512 + i];
    }
    float* dst = zq + ((size_t)b * 1024 + t) * 128;
    #pragma unroll
    for (int c = 0; c < 4; ++c) dst[o0 + c] = acc[c];
}

// ---------------------------------------------------------------------------
// VQ: 64 positions/block, 16 code-tiles of 64, 4x4 register dot tiles.
// dist via cn - 2*dot (||z||^2 row-constant); tie -> lowest index.
// Writes argmin indices, quantized fp32 [B,D,L] (final output), hist, loss.
// ---------------------------------------------------------------------------
__global__ __launch_bounds__(256) void vq_k(
    const float* __restrict__ z,       // [32768,128]
    const float* __restrict__ cb,      // [1024,128]
    float* __restrict__ out_q,         // [B,128,1024]
    float* __restrict__ lossAcc,
    unsigned int* __restrict__ hist,
    int* __restrict__ ip_out)
{
    const int tid = threadIdx.x;
    const int pbase = blockIdx.x * 64;
    __shared__ float zs[64 * 129];
    __shared__ float cbs[64 * 129];
    __shared__ float cn[64];
    __shared__ float rd[256];
    __shared__ int   ri[256];
    __shared__ int   ip[64];

    for (int f = tid; f < 64 * 128; f += 256) {
        int p = f >> 7, d = f & 127;
        zs[p * 129 + d] = z[(size_t)pbase * 128 + f];
    }

    float mind[4]; int minc[4];
    #pragma unroll
    for (int a = 0; a < 4; ++a) { mind[a] = 3.4e38f; minc[a] = 0; }
    const int tp = tid >> 4, tr = tid & 15;
    const int prow = tp * 4, crow = tr * 4;

    for (int ct = 0; ct < 16; ++ct) {
        __syncthreads();
        for (int f = tid; f < 64 * 128; f += 256) {
            int c = f >> 7, d = f & 127;
            cbs[c * 129 + d] = cb[((size_t)ct * 64 + c) * 128 + d];
        }
        __syncthreads();
        if (tid < 64) {
            float s = 0.f;
            for (int d = 0; d < 128; ++d) { float v = cbs[tid * 129 + d]; s += v * v; }
            cn[tid] = s;
        }
        __syncthreads();
        float dot[4][4];
        #pragma unroll
        for (int a = 0; a < 4; ++a)
            #pragma unroll
            for (int e = 0; e < 4; ++e) dot[a][e] = 0.f;
        for (int d = 0; d < 128; ++d) {
            float za[4], cc[4];
            #pragma unroll
            for (int a = 0; a < 4; ++a) za[a] = zs[(prow + a) * 129 + d];
            #pragma unroll
            for (int e = 0; e < 4; ++e) cc[e] = cbs[(crow + e) * 129 + d];
            #pragma unroll
            for (int a = 0; a < 4; ++a)
                #pragma unroll
                for (int e = 0; e < 4; ++e) dot[a][e] += za[a] * cc[e];
        }
        #pragma unroll
        for (int e = 0; e < 4; ++e) {
            int c = ct * 64 + crow + e;
            float cne = cn[crow + e];
            #pragma unroll
            for (int a = 0; a < 4; ++a) {
                float dist = cne - 2.0f * dot[a][e];
                if (dist < mind[a]) { mind[a] = dist; minc[a] = c; }
            }
        }
    }

    for (int a = 0; a < 4; ++a) {
        __syncthreads();
        rd[tid] = mind[a]; ri[tid] = minc[a];
        __syncthreads();
        if (tr == 0) {
            float bd = rd[tid]; int bi = ri[tid];
            for (int u = 1; u < 16; ++u) {
                float dv = rd[tid + u]; int iv = ri[tid + u];
                if (dv < bd || (dv == bd && iv < bi)) { bd = dv; bi = iv; }
            }
            ip[prow + a] = bi;
            atomicAdd(&hist[bi], 1u);
        }
    }
    __syncthreads();

    if (tid < 64) ip_out[pbase + tid] = ip[tid];

    float lp = 0.f;
    for (int f = tid; f < 64 * 128; f += 256) {
        int p = f >> 7, d = f & 127;
        int gp = pbase + p, b = gp >> 10, l = gp & 1023;
        float qv = cb[(size_t)ip[p] * 128 + d];
        float zv = zs[p * 129 + d];
        float df = qv - zv; lp += df * df;
        out_q[(((size_t)b * 128 + d) << 10) + l] = qv;
    }
    rd[tid] = lp; __syncthreads();
    for (int off = 128; off > 0; off >>= 1) {
        if (tid < off) rd[tid] += rd[tid + off];
        __syncthreads();
    }
    if (tid == 0) atomicAdd(lossAcc, rd[0]);
}

// one-hot enc write (fp32) from indices; enc region was scratch until now.
__global__ __launch_bounds__(256) void enc_k(
    const int* __restrict__ ip, float2* __restrict__ enc)
{
    size_t idx = (size_t)blockIdx.x * 256 + threadIdx.x;   // 16,777,216 float2
    int p  = (int)(idx >> 9);
    int q2 = (int)(idx & 511);
    int best = ip[p];
    int c0 = q2 * 2;
    float2 v;
    v.x = (c0     == best) ? 1.0f : 0.0f;
    v.y = (c0 + 1 == best) ? 1.0f : 0.0f;
    enc[idx] = v;
}

// mean over L=1024 of fp32 [B,D,L]; one block per (b,d)
__global__ __launch_bounds__(256) void pool_k(const float* __restrict__ q, float* __restrict__ zp)
{
    int tid = threadIdx.x;
    const float* row = q + (size_t)blockIdx.x * 1024;
    float s = 0.f;
    for (int l = tid; l < 1024; l += 256) s += row[l];
    __shared__ float rs[256];
    rs[tid] = s; __syncthreads();
    for (int off = 128; off > 0; off >>= 1) {
        if (tid < off) rs[tid] += rs[tid + off];
        __syncthreads();
    }
    if (tid == 0) zp[blockIdx.x] = rs[0] * (1.0f / 1024.0f);
}

// behavior MLP head, single block
__global__ __launch_bounds__(256) void beh_k(
    const float* __restrict__ zp,
    const float* __restrict__ w1, const float* __restrict__ b1,
    const float* __restrict__ w2, const float* __restrict__ b2,
    const float* __restrict__ w3, const float* __restrict__ b3,
    float* __restrict__ out)
{
    __shared__ float zs[32 * 128];
    __shared__ float h1s[32 * 128];
    __shared__ float h2s[32 * 64];
    int tid = threadIdx.x;
    for (int f = tid; f < 4096; f += 256) zs[f] = zp[f];
    __syncthreads();
    for (int f = tid; f < 4096; f += 256) {
        int bi = f >> 7, j = f & 127;
        float acc = b1[j];
        for (int d = 0; d < 128; ++d) acc += zs[bi * 128 + d] * w1[j * 128 + d];
        h1s[f] = fmaxf(acc, 0.f);
    }
    __syncthreads();
    for (int f = tid; f < 2048; f += 256) {
        int bi = f >> 6, j = f & 63;
        float acc = b2[j];
        for (int d = 0; d < 128; ++d) acc += h1s[bi * 128 + d] * w2[j * 128 + d];
        h2s[f] = fmaxf(acc, 0.f);
    }
    __syncthreads();
    if (tid < 128) {
        int bi = tid >> 2, j = tid & 3;
        float acc = b3[j];
        for (int d = 0; d < 64; ++d) acc += h2s[bi * 64 + d] * w3[j * 64 + d];
        out[tid] = acc;
    }
}

__global__ __launch_bounds__(1024) void init_k(unsigned int* hist, float* lossAcc)
{
    hist[threadIdx.x] = 0u;
    if (threadIdx.x == 0) *lossAcc = 0.f;
}

__global__ __launch_bounds__(1024) void fin_k(
    const unsigned int* __restrict__ hist, const float* __restrict__ lossAcc,
    float* __restrict__ out_loss, float* __restrict__ out_perp)
{
    __shared__ float rs[1024];
    int tid = threadIdx.x;
    float avg = (float)hist[tid] * (1.0f / 32768.0f);
    rs[tid] = avg * logf(avg + 1e-10f);
    __syncthreads();
    for (int off = 512; off > 0; off >>= 1) {
        if (tid < off) rs[tid] += rs[tid + off];
        __syncthreads();
    }
    if (tid == 0) {
        out_perp[0] = expf(-rs[0]);
        out_loss[0] = 0.25f * lossAcc[0] * (1.0f / 4194304.0f);
    }
}

// ---------------------------------------------------------------------------
extern "C" void kernel_launch(void* const* d_in, const int* in_sizes, int n_in,
                              void* d_out, int out_size, void* d_ws, size_t ws_size,
                              hipStream_t stream)
{
    const float* X    = (const float*)d_in[0];
    const float* e1w  = (const float*)d_in[1];  const float* e1b = (const float*)d_in[2];
    const float* e2w  = (const float*)d_in[3];  const float* e2b = (const float*)d_in[4];
    const float* e3w  = (const float*)d_in[5];  const float* e3b = (const float*)d_in[6];
    const float* r0g1g = (const float*)d_in[7];  const float* r0g1b = (const float*)d_in[8];
    const float* r0c1w = (const float*)d_in[9];
    const float* r0g2g = (const float*)d_in[10]; const float* r0g2b = (const float*)d_in[11];
    const float* r0c2w = (const float*)d_in[12];
    const float* r1g1g = (const float*)d_in[13]; const float* r1g1b = (const float*)d_in[14];
    const float* r1c1w = (const float*)d_in[15];
    const float* r1g2g = (const float*)d_in[16]; const float* r1g2b = (const float*)d_in[17];
    const float* r1c2w = (const float*)d_in[18];
    const float* pvw  = (const float*)d_in[19]; const float* pvb = (const float*)d_in[20];
    const float* CB   = (const float*)d_in[21];
    const float* d1w  = (const float*)d_in[22]; const float* d1b = (const float*)d_in[23];
    const float* d2w  = (const float*)d_in[24]; const float* d2b = (const float*)d_in[25];
    const float* d3w  = (const float*)d_in[26]; const float* d3b = (const float*)d_in[27];
    const float* bh1w = (const float*)d_in[28]; const float* bh1b = (const float*)d_in[29];
    const float* bh2w = (const float*)d_in[30]; const float* bh2b = (const float*)d_in[31];
    const float* bh3w = (const float*)d_in[32]; const float* bh3b = (const float*)d_in[33];

    // ---- output regions (fp32 elements) ----
    float* out = (float*)d_out;
    const size_t N_XREC = 16777216ull, N_Q = 4194304ull, N_ENC = 33554432ull;
    float* out_loss = out;
    float* out_xrec = out + 1;                          // 64 MiB region
    float* out_perp = out + 1 + N_XREC;
    float* out_q    = out + 2 + N_XREC;                 // 16 MiB region
    float* out_enc  = out + 2 + N_XREC + N_Q;           // 128 MiB region
    float* out_beh  = out + 2 + N_XREC + N_Q + N_ENC;

    // ---- d_out scratch staging (serial lifetimes, per-quarter schedule) ----
    // xrec region (16,777,216 floats): h1q/h3q [0..4,194,304) ; t2q [4,194,304..5,242,880)
    float* h1q = out_xrec;
    float* h3q = out_xrec;
    float* t2q = out_xrec + 4194304;
    // enc region (33,554,432 floats): z [0..4.19M) ; h2q [4.19M..8.39M) ;
    //   d1o [8.39M..16.78M) ; d2o [16.78M..25.17M) ; finally one-hot output
    float* z   = out_enc;
    float* h2q = out_enc + 4194304;
    float* d1o = out_enc + 8388608;
    float* d2o = out_enc + 16777216;

    // ---- d_ws: smalls ONLY (~190 KB at offset 0) ----
    float* W = (float*)d_ws;
    float* lossA = W;                              // 1 (+pad 16)
    unsigned int* hist = (unsigned int*)(W + 16);  // 1,024
    float* zp   = W + 16 + 1024;                   // 4,096
    int* ipArr  = (int*)(W + 16 + 1024 + 4096);    // 32,768
    float* scA  = W + 16 + 1024 + 4096 + 32768;    // 4,096 (8 local batches x 512)
    float* shA  = scA + 4096;                      // 4,096
    float* scB  = shA + 4096;                      // 1,024 (8 x 128)
    float* shB  = scB + 1024;                      // 1,024

    init_k<<<dim3(1), dim3(1024), 0, stream>>>(hist, lossA);

    // ---- encoder + res blocks + pre-VQ, per batch-quarter (8 samples) ----
    for (int q = 0; q < 4; ++q) {
        const float* Xq = X + (size_t)q * 8 * 128 * 4096;
        conv1d_k<7><<<dim3(16, 32, 8), 256, 0, stream>>>(
            Xq, e1w, e1b, h1q, nullptr, nullptr, nullptr,
            128, 4096, 4096, 1, 3, 1, 128);
        conv1d_k<5><<<dim3(8, 64, 8), 256, 0, stream>>>(
            h1q, e2w, e2b, h2q, nullptr, nullptr, nullptr,
            128, 4096, 2048, 2, 2, 1, 256);
        conv1d_k<3><<<dim3(4, 128, 8), 256, 0, stream>>>(
            h2q, e3w, e3b, h3q, nullptr, nullptr, nullptr,
            256, 2048, 1024, 2, 1, 0, 512);

        // res block 0
        gnstats_k<<<dim3(64), 256, 0, stream>>>(h3q, r0g1g, r0g1b, scA, shA, 512, 1024, 8);
        conv1d_k<3><<<dim3(4, 32, 8), 256, 0, stream>>>(
            h3q, r0c1w, nullptr, t2q, scA, shA, nullptr,
            512, 1024, 1024, 1, 1, 0, 128);
        gnstats_k<<<dim3(64), 256, 0, stream>>>(t2q, r0g2g, r0g2b, scB, shB, 128, 1024, 8);
        conv1d_k<1><<<dim3(4, 128, 8), 256, 0, stream>>>(
            t2q, r0c2w, nullptr, h3q, scB, shB, h3q,
            128, 1024, 1024, 1, 0, 0, 512);

        // res block 1
        gnstats_k<<<dim3(64), 256, 0, stream>>>(h3q, r1g1g, r1g1b, scA, shA, 512, 1024, 8);
        conv1d_k<3><<<dim3(4, 32, 8), 256, 0, stream>>>(
            h3q, r1c1w, nullptr, t2q, scA, shA, nullptr,
            512, 1024, 1024, 1, 1, 0, 128);
        gnstats_k<<<dim3(64), 256, 0, stream>>>(t2q, r1g2g, r1g2b, scB, shB, 128, 1024, 8);
        conv1d_k<1><<<dim3(4, 128, 8), 256, 0, stream>>>(
            t2q, r1c2w, nullptr, h3q, scB, shB, h3q,
            128, 1024, 1024, 1, 0, 0, 512);

        // pre-VQ 1x1 conv -> z quarter (contiguous [pos,128])
        prevq_k<<<dim3(4, 32, 8), 256, 0, stream>>>(
            h3q, pvw, pvb, z + (size_t)q * 8192 * 128);
    }

    // ---- VQ: writes out_q (final fp32), hist, loss, indices ----
    vq_k<<<dim3(512), 256, 0, stream>>>(z, CB, out_q, lossA, hist, ipArr);

    // ---- behavior head ----
    pool_k<<<dim3(4096), 256, 0, stream>>>(out_q, zp);
    beh_k<<<dim3(1), 256, 0, stream>>>(zp, bh1w, bh1b, bh2w, bh2b, bh3w, bh3b, out_beh);

    // ---- decoder, per batch-quarter (z/h2q dead; slots in enc region) ----
    // convT layers in parity-split form: thread owns t2, emits {2t2, 2t2+1}.
    for (int q = 0; q < 4; ++q) {
        convt2_k<3><<<dim3(4, 64, 8), 256, 0, stream>>>(
            out_q + (size_t)q * 1048576, d1w, d1b, d1o, 128, 1024, 512);
        convt2_k<5><<<dim3(8, 32, 8), 256, 0, stream>>>(
            d1o, d2w, d2b, d2o, 512, 2048, 256);
        conv1d_k<7><<<dim3(16, 32, 8), 256, 0, stream>>>(
            d2o, d3w, d3b, out_xrec + (size_t)q * 4194304, nullptr, nullptr, nullptr,
            256, 4096, 4096, 1, 3, 0, 128);
    }

    // ---- one-hot enc (overwrites enc-region scratch with the real output) ----
    enc_k<<<dim3(65536), 256, 0, stream>>>(ipArr, (float2*)out_enc);

    // ---- loss + perplexity ----
    fin_k<<<dim3(1), 1024, 0, stream>>>(hist, lossA, out_loss, out_perp);
}

// Round 2
// 16937.596 us; speedup vs baseline: 1.4604x; 1.0315x over previous
//
#include <hip/hip_runtime.h>

// All tensors fp32 (per the reference: inputs, weights, outputs all float32).

// ---------------------------------------------------------------------------
// Direct conv1d, register-blocked: each thread computes TT consecutive output
// positions x 4 output channels, with a sliding input window in registers.
// Optional fused input-side GN+ReLU (scale/shift per (b_local,cin)), residual
// add, output relu. All window indices compile-time static (K, TT, S template
// params) so win[] stays in VGPRs.
// ---------------------------------------------------------------------------
template<int K, int TT, int S>
__global__ __launch_bounds__(256) void conv2_k(
    const float* __restrict__ in, const float* __restrict__ w,
    const float* __restrict__ bias, float* __restrict__ out,
    const float* __restrict__ scale, const float* __restrict__ shift,
    const float* __restrict__ resid,
    int Cin, int Lin, int Lout, int pad, int relu_out, int Cout)
{
    constexpr int WN = (TT - 1) * S + K;   // input window per thread
    int t0 = (blockIdx.x * 256 + threadIdx.x) * TT;
    if (t0 >= Lout) return;
    int o0 = blockIdx.y * 4;
    int b  = blockIdx.z;

    float acc[4][TT];
    #pragma unroll
    for (int c = 0; c < 4; ++c) {
        float bv = bias ? bias[o0 + c] : 0.0f;
        #pragma unroll
        for (int tt = 0; tt < TT; ++tt) acc[c][tt] = bv;
    }

    const float* inb = in + (size_t)b * Cin * Lin;
    const float* wb  = w + (size_t)o0 * Cin * K;
    const size_t wstride = (size_t)Cin * K;

    const int p0 = t0 * S - pad;
    const bool fast = (p0 >= 0) && (p0 + WN <= Lin);

    for (int i = 0; i < Cin; ++i) {
        const float* xi = inb + (size_t)i * Lin;
        float win[WN];
        #pragma unroll
        for (int j = 0; j < WN; ++j) {
            int p = p0 + j;
            bool ok = fast || (p >= 0 && p < Lin);
            win[j] = ok ? xi[p] : 0.0f;
        }
        if (scale) {
            float sc = scale[b * Cin + i], sh = shift[b * Cin + i];
            #pragma unroll
            for (int j = 0; j < WN; ++j) {
                int p = p0 + j;
                bool ok = fast || (p >= 0 && p < Lin);
                win[j] = ok ? fmaxf(win[j] * sc + sh, 0.0f) : 0.0f;
            }
        }
        const float* wi = wb + (size_t)i * K;
        #pragma unroll
        for (int k = 0; k < K; ++k) {
            float wv[4];
            #pragma unroll
            for (int c = 0; c < 4; ++c) wv[c] = wi[c * wstride + k];
            #pragma unroll
            for (int tt = 0; tt < TT; ++tt) {
                float v = win[tt * S + k];
                #pragma unroll
                for (int c = 0; c < 4; ++c) acc[c][tt] += v * wv[c];
            }
        }
    }

    if (resid) {
        size_t r0 = ((size_t)b * Cout + o0) * Lout + t0;
        #pragma unroll
        for (int c = 0; c < 4; ++c)
            #pragma unroll
            for (int tt = 0; tt < TT; ++tt)
                acc[c][tt] += resid[r0 + (size_t)c * Lout + tt];
    }
    if (relu_out) {
        #pragma unroll
        for (int c = 0; c < 4; ++c)
            #pragma unroll
            for (int tt = 0; tt < TT; ++tt) acc[c][tt] = fmaxf(acc[c][tt], 0.f);
    }
    size_t i0 = ((size_t)b * Cout + o0) * Lout + t0;
    #pragma unroll
    for (int c = 0; c < 4; ++c)
        #pragma unroll
        for (int tt = 0; tt < TT; ++tt)
            out[i0 + (size_t)c * Lout + tt] = acc[c][tt];   // dst may be 4B-aligned only
}

// ---------------------------------------------------------------------------
// ConvTranspose1d stride-2, parity-split, t2-PAIR per thread: thread owns
// input indices (t2, t2+1) -> 4 consecutive outputs 2t2..2t2+3 for 8 output
// channels (32 accumulators). One float4 store per channel (dst 16B-aligned).
//   K=3 (pad_lo=1): even(t2)=w1*x[t2]; odd(t2)=w0*x[t2]+w2*x[t2+1]
//   K=5 (pad_lo=2): even(t2)=w0*x[t2-1]+w2*x[t2]+w4*x[t2+1]; odd(t2)=w1*x[t2]+w3*x[t2+1]
// ---------------------------------------------------------------------------
template<int K>
__global__ __launch_bounds__(256) void convt3_k(
    const float* __restrict__ in, const float* __restrict__ w,
    const float* __restrict__ bias, float* __restrict__ out,
    int Cin, int Lin, int Cout)
{
    constexpr int WN = (K == 5) ? 4 : 3;
    int t2 = (blockIdx.x * 256 + threadIdx.x) * 2;   // first of the pair
    if (t2 >= Lin) return;
    int o0 = blockIdx.y * 8;
    int b  = blockIdx.z;
    const int Lout = 2 * Lin;

    const float* inb = in + (size_t)b * Cin * Lin;
    const float* wb  = w + (size_t)o0 * Cin * K;
    const size_t ws  = (size_t)Cin * K;

    float acc[8][4];
    #pragma unroll
    for (int c = 0; c < 8; ++c) {
        float bv = bias[o0 + c];
        #pragma unroll
        for (int u = 0; u < 4; ++u) acc[c][u] = bv;
    }

    const int q0 = (K == 5) ? (t2 - 1) : t2;
    const bool fast = (q0 >= 0) && (q0 + WN <= Lin);

    for (int i = 0; i < Cin; ++i) {
        const float* xi = inb + (size_t)i * Lin;
        float win[WN];
        #pragma unroll
        for (int j = 0; j < WN; ++j) {
            int p = q0 + j;
            bool ok = fast || (p >= 0 && p < Lin);
            win[j] = ok ? xi[p] : 0.0f;
        }
        const float* wi = wb + (size_t)i * K;
        #pragma unroll
        for (int c = 0; c < 8; ++c) {
            const float* wc = wi + (size_t)c * ws;
            if constexpr (K == 5) {
                float w0 = wc[0], w1 = wc[1], w2 = wc[2], w3 = wc[3], w4 = wc[4];
                acc[c][0] += w0 * win[0] + w2 * win[1] + w4 * win[2];
                acc[c][1] += w1 * win[1] + w3 * win[2];
                acc[c][2] += w0 * win[1] + w2 * win[2] + w4 * win[3];
                acc[c][3] += w1 * win[2] + w3 * win[3];
            } else {
                float w0 = wc[0], w1 = wc[1], w2 = wc[2];
                acc[c][0] += w1 * win[0];
                acc[c][1] += w0 * win[0] + w2 * win[1];
                acc[c][2] += w1 * win[1];
                acc[c][3] += w0 * win[1] + w2 * win[2];
            }
        }
    }
    size_t base = ((size_t)b * Cout + o0) * (size_t)Lout + (size_t)(2 * t2);
    #pragma unroll
    for (int c = 0; c < 8; ++c) {
        float4 v;
        v.x = fmaxf(acc[c][0], 0.f);
        v.y = fmaxf(acc[c][1], 0.f);
        v.z = fmaxf(acc[c][2], 0.f);
        v.w = fmaxf(acc[c][3], 0.f);
        *(float4*)(out + base + (size_t)c * Lout) = v;
    }
}

// ---------------------------------------------------------------------------
// GroupNorm stats -> per-(b_local,c) scale/shift (eps 1e-5)
// ---------------------------------------------------------------------------
__global__ __launch_bounds__(256) void gnstats_k(
    const float* __restrict__ x, const float* __restrict__ g,
    const float* __restrict__ be, float* __restrict__ scale,
    float* __restrict__ shift, int C, int L, int G)
{
    int tid = threadIdx.x;
    int b = blockIdx.x / G, gr = blockIdx.x % G;
    int cpg = C / G;
    size_t n = (size_t)cpg * L;
    const float* base = x + ((size_t)b * C + (size_t)gr * cpg) * L;
    float s = 0.f, s2 = 0.f;
    for (size_t idx = tid; idx < n; idx += 256) { float v = base[idx]; s += v; s2 += v * v; }
    __shared__ float rs[256], rq[256];
    rs[tid] = s; rq[tid] = s2; __syncthreads();
    for (int off = 128; off > 0; off >>= 1) {
        if (tid < off) { rs[tid] += rs[tid + off]; rq[tid] += rq[tid + off]; }
        __syncthreads();
    }
    float mean = rs[0] / (float)n;
    float var  = rq[0] / (float)n - mean * mean;
    float inv  = rsqrtf(var + 1e-5f);
    if (tid < cpg) {
        int c = gr * cpg + tid;
        float ga = g[c], bb = be[c];
        scale[b * C + c] = inv * ga;
        shift[b * C + c] = bb - mean * inv * ga;
    }
}

// ---------------------------------------------------------------------------
// pre-VQ 1x1 conv on one batch-quarter (8 samples); writes z [pos,128] fp32.
// ---------------------------------------------------------------------------
__global__ __launch_bounds__(256) void prevq_k(
    const float* __restrict__ h3q, const float* __restrict__ w,
    const float* __restrict__ bias, float* __restrict__ zq)
{
    int t = blockIdx.x * 256 + threadIdx.x;   // < 1024
    int o0 = blockIdx.y * 4;                  // < 128
    int b  = blockIdx.z;                      // < 8 (local)

    float acc[4];
    #pragma unroll
    for (int c = 0; c < 4; ++c) acc[c] = bias[o0 + c];
    const float* inb = h3q + (size_t)b * 512 * 1024;
    for (int i = 0; i < 512; ++i) {
        float v = inb[(size_t)i * 1024 + t];
        #pragma unroll
        for (int c = 0; c < 4; ++c) acc[c] += v * w[(size_t)(o0 + c) * 512 + i];
    }
    float* dst = zq + ((size_t)b * 1024 + t) * 128;
    #pragma unroll
    for (int c = 0; c < 4; ++c) dst[o0 + c] = acc[c];
}

// ---------------------------------------------------------------------------
// VQ: 64 positions/block, 16 code-tiles of 64, 4x4 register dot tiles.
// dist via cn - 2*dot (||z||^2 row-constant); tie -> lowest index.
// Writes argmin indices, quantized fp32 [B,D,L] (final output), hist, loss.
// ---------------------------------------------------------------------------
__global__ __launch_bounds__(256) void vq_k(
    const float* __restrict__ z,       // [32768,128]
    const float* __restrict__ cb,      // [1024,128]
    float* __restrict__ out_q,         // [B,128,1024]
    float* __restrict__ lossAcc,
    unsigned int* __restrict__ hist,
    int* __restrict__ ip_out)
{
    const int tid = threadIdx.x;
    const int pbase = blockIdx.x * 64;
    __shared__ float zs[64 * 129];
    __shared__ float cbs[64 * 129];
    __shared__ float cn[64];
    __shared__ float rd[256];
    __shared__ int   ri[256];
    __shared__ int   ip[64];

    for (int f = tid; f < 64 * 128; f += 256) {
        int p = f >> 7, d = f & 127;
        zs[p * 129 + d] = z[(size_t)pbase * 128 + f];
    }

    float mind[4]; int minc[4];
    #pragma unroll
    for (int a = 0; a < 4; ++a) { mind[a] = 3.4e38f; minc[a] = 0; }
    const int tp = tid >> 4, tr = tid & 15;
    const int prow = tp * 4, crow = tr * 4;

    for (int ct = 0; ct < 16; ++ct) {
        __syncthreads();
        for (int f = tid; f < 64 * 128; f += 256) {
            int c = f >> 7, d = f & 127;
            cbs[c * 129 + d] = cb[((size_t)ct * 64 + c) * 128 + d];
        }
        __syncthreads();
        if (tid < 64) {
            float s = 0.f;
            for (int d = 0; d < 128; ++d) { float v = cbs[tid * 129 + d]; s += v * v; }
            cn[tid] = s;
        }
        __syncthreads();
        float dot[4][4];
        #pragma unroll
        for (int a = 0; a < 4; ++a)
            #pragma unroll
            for (int e = 0; e < 4; ++e) dot[a][e] = 0.f;
        for (int d = 0; d < 128; ++d) {
            float za[4], cc[4];
            #pragma unroll
            for (int a = 0; a < 4; ++a) za[a] = zs[(prow + a) * 129 + d];
            #pragma unroll
            for (int e = 0; e < 4; ++e) cc[e] = cbs[(crow + e) * 129 + d];
            #pragma unroll
            for (int a = 0; a < 4; ++a)
                #pragma unroll
                for (int e = 0; e < 4; ++e) dot[a][e] += za[a] * cc[e];
        }
        #pragma unroll
        for (int e = 0; e < 4; ++e) {
            int c = ct * 64 + crow + e;
            float cne = cn[crow + e];
            #pragma unroll
            for (int a = 0; a < 4; ++a) {
                float dist = cne - 2.0f * dot[a][e];
                if (dist < mind[a]) { mind[a] = dist; minc[a] = c; }
            }
        }
    }

    for (int a = 0; a < 4; ++a) {
        __syncthreads();
        rd[tid] = mind[a]; ri[tid] = minc[a];
        __syncthreads();
        if (tr == 0) {
            float bd = rd[tid]; int bi = ri[tid];
            for (int u = 1; u < 16; ++u) {
                float dv = rd[tid + u]; int iv = ri[tid + u];
                if (dv < bd || (dv == bd && iv < bi)) { bd = dv; bi = iv; }
            }
            ip[prow + a] = bi;
            atomicAdd(&hist[bi], 1u);
        }
    }
    __syncthreads();

    if (tid < 64) ip_out[pbase + tid] = ip[tid];

    float lp = 0.f;
    for (int f = tid; f < 64 * 128; f += 256) {
        int p = f >> 7, d = f & 127;
        int gp = pbase + p, b = gp >> 10, l = gp & 1023;
        float qv = cb[(size_t)ip[p] * 128 + d];
        float zv = zs[p * 129 + d];
        float df = qv - zv; lp += df * df;
        out_q[(((size_t)b * 128 + d) << 10) + l] = qv;
    }
    rd[tid] = lp; __syncthreads();
    for (int off = 128; off > 0; off >>= 1) {
        if (tid < off) rd[tid] += rd[tid + off];
        __syncthreads();
    }
    if (tid == 0) atomicAdd(lossAcc, rd[0]);
}

// one-hot enc write (fp32) from indices; enc region was scratch until now.
__global__ __launch_bounds__(256) void enc_k(
    const int* __restrict__ ip, float2* __restrict__ enc)
{
    size_t idx = (size_t)blockIdx.x * 256 + threadIdx.x;   // 16,777,216 float2
    int p  = (int)(idx >> 9);
    int q2 = (int)(idx & 511);
    int best = ip[p];
    int c0 = q2 * 2;
    float2 v;
    v.x = (c0     == best) ? 1.0f : 0.0f;
    v.y = (c0 + 1 == best) ? 1.0f : 0.0f;
    enc[idx] = v;
}

// mean over L=1024 of fp32 [B,D,L]; one block per (b,d)
__global__ __launch_bounds__(256) void pool_k(const float* __restrict__ q, float* __restrict__ zp)
{
    int tid = threadIdx.x;
    const float* row = q + (size_t)blockIdx.x * 1024;
    float s = 0.f;
    for (int l = tid; l < 1024; l += 256) s += row[l];
    __shared__ float rs[256];
    rs[tid] = s; __syncthreads();
    for (int off = 128; off > 0; off >>= 1) {
        if (tid < off) rs[tid] += rs[tid + off];
        __syncthreads();
    }
    if (tid == 0) zp[blockIdx.x] = rs[0] * (1.0f / 1024.0f);
}

// behavior MLP head, single block
__global__ __launch_bounds__(256) void beh_k(
    const float* __restrict__ zp,
    const float* __restrict__ w1, const float* __restrict__ b1,
    const float* __restrict__ w2, const float* __restrict__ b2,
    const float* __restrict__ w3, const float* __restrict__ b3,
    float* __restrict__ out)
{
    __shared__ float zs[32 * 128];
    __shared__ float h1s[32 * 128];
    __shared__ float h2s[32 * 64];
    int tid = threadIdx.x;
    for (int f = tid; f < 4096; f += 256) zs[f] = zp[f];
    __syncthreads();
    for (int f = tid; f < 4096; f += 256) {
        int bi = f >> 7, j = f & 127;
        float acc = b1[j];
        for (int d = 0; d < 128; ++d) acc += zs[bi * 128 + d] * w1[j * 128 + d];
        h1s[f] = fmaxf(acc, 0.f);
    }
    __syncthreads();
    for (int f = tid; f < 2048; f += 256) {
        int bi = f >> 6, j = f & 63;
        float acc = b2[j];
        for (int d = 0; d < 128; ++d) acc += h1s[bi * 128 + d] * w2[j * 128 + d];
        h2s[f] = fmaxf(acc, 0.f);
    }
    __syncthreads();
    if (tid < 128) {
        int bi = tid >> 2, j = tid & 3;
        float acc = b3[j];
        for (int d = 0; d < 64; ++d) acc += h2s[bi * 64 + d] * w3[j * 64 + d];
        out[tid] = acc;
    }
}

__global__ __launch_bounds__(1024) void init_k(unsigned int* hist, float* lossAcc)
{
    hist[threadIdx.x] = 0u;
    if (threadIdx.x == 0) *lossAcc = 0.f;
}

__global__ __launch_bounds__(1024) void fin_k(
    const unsigned int* __restrict__ hist, const float* __restrict__ lossAcc,
    float* __restrict__ out_loss, float* __restrict__ out_perp)
{
    __shared__ float rs[1024];
    int tid = threadIdx.x;
    float avg = (float)hist[tid] * (1.0f / 32768.0f);
    rs[tid] = avg * logf(avg + 1e-10f);
    __syncthreads();
    for (int off = 512; off > 0; off >>= 1) {
        if (tid < off) rs[tid] += rs[tid + off];
        __syncthreads();
    }
    if (tid == 0) {
        out_perp[0] = expf(-rs[0]);
        out_loss[0] = 0.25f * lossAcc[0] * (1.0f / 4194304.0f);
    }
}

// ---------------------------------------------------------------------------
extern "C" void kernel_launch(void* const* d_in, const int* in_sizes, int n_in,
                              void* d_out, int out_size, void* d_ws, size_t ws_size,
                              hipStream_t stream)
{
    const float* X    = (const float*)d_in[0];
    const float* e1w  = (const float*)d_in[1];  const float* e1b = (const float*)d_in[2];
    const float* e2w  = (const float*)d_in[3];  const float* e2b = (const float*)d_in[4];
    const float* e3w  = (const float*)d_in[5];  const float* e3b = (const float*)d_in[6];
    const float* r0g1g = (const float*)d_in[7];  const float* r0g1b = (const float*)d_in[8];
    const float* r0c1w = (const float*)d_in[9];
    const float* r0g2g = (const float*)d_in[10]; const float* r0g2b = (const float*)d_in[11];
    const float* r0c2w = (const float*)d_in[12];
    const float* r1g1g = (const float*)d_in[13]; const float* r1g1b = (const float*)d_in[14];
    const float* r1c1w = (const float*)d_in[15];
    const float* r1g2g = (const float*)d_in[16]; const float* r1g2b = (const float*)d_in[17];
    const float* r1c2w = (const float*)d_in[18];
    const float* pvw  = (const float*)d_in[19]; const float* pvb = (const float*)d_in[20];
    const float* CB   = (const float*)d_in[21];
    const float* d1w  = (const float*)d_in[22]; const float* d1b = (const float*)d_in[23];
    const float* d2w  = (const float*)d_in[24]; const float* d2b = (const float*)d_in[25];
    const float* d3w  = (const float*)d_in[26]; const float* d3b = (const float*)d_in[27];
    const float* bh1w = (const float*)d_in[28]; const float* bh1b = (const float*)d_in[29];
    const float* bh2w = (const float*)d_in[30]; const float* bh2b = (const float*)d_in[31];
    const float* bh3w = (const float*)d_in[32]; const float* bh3b = (const float*)d_in[33];

    // ---- output regions (fp32 elements) ----
    float* out = (float*)d_out;
    const size_t N_XREC = 16777216ull, N_Q = 4194304ull, N_ENC = 33554432ull;
    float* out_loss = out;
    float* out_xrec = out + 1;                          // 64 MiB region
    float* out_perp = out + 1 + N_XREC;
    float* out_q    = out + 2 + N_XREC;                 // 16 MiB region
    float* out_enc  = out + 2 + N_XREC + N_Q;           // 128 MiB region
    float* out_beh  = out + 2 + N_XREC + N_Q + N_ENC;

    // ---- d_out scratch staging (serial lifetimes, per-quarter schedule) ----
    // Scratch pointers shifted so they are 16B-aligned (d_out is >=256B
    // aligned; out_xrec=out+1 and out_enc=out+2+N_XREC are not).
    // xrec region: h1q/h3q at out+4 [4,194,304) ; t2q following
    float* h1q = out + 4;                    // 16B-aligned
    float* h3q = h1q;
    float* t2q = h1q + 4194304;              // 16B-aligned
    // enc region: z at out_enc+2 (16B-aligned); h2q/d1o/d2o follow; all dead
    // before enc_k overwrites the region with the real one-hot output.
    float* z   = out_enc + 2;                // 16B-aligned
    float* h2q = z + 4194304;
    float* d1o = z + 8388608;
    float* d2o = z + 16777216;

    // ---- d_ws: smalls ONLY (~190 KB at offset 0) ----
    float* W = (float*)d_ws;
    float* lossA = W;                              // 1 (+pad 16)
    unsigned int* hist = (unsigned int*)(W + 16);  // 1,024
    float* zp   = W + 16 + 1024;                   // 4,096
    int* ipArr  = (int*)(W + 16 + 1024 + 4096);    // 32,768
    float* scA  = W + 16 + 1024 + 4096 + 32768;    // 4,096 (8 local batches x 512)
    float* shA  = scA + 4096;                      // 4,096
    float* scB  = shA + 4096;                      // 1,024 (8 x 128)
    float* shB  = scB + 1024;                      // 1,024

    init_k<<<dim3(1), dim3(1024), 0, stream>>>(hist, lossA);

    // ---- encoder + res blocks + pre-VQ, per batch-quarter (8 samples) ----
    for (int q = 0; q < 4; ++q) {
        const float* Xq = X + (size_t)q * 8 * 128 * 4096;
        // e1: K7 s1 p3, 128->128, L4096. 4 t x 4 co per thread.
        conv2_k<7, 4, 1><<<dim3(4, 32, 8), 256, 0, stream>>>(
            Xq, e1w, e1b, h1q, nullptr, nullptr, nullptr,
            128, 4096, 4096, 3, 1, 128);
        // e2: K5 s2 p2, 128->256, Lout2048.
        conv2_k<5, 4, 2><<<dim3(2, 64, 8), 256, 0, stream>>>(
            h1q, e2w, e2b, h2q, nullptr, nullptr, nullptr,
            128, 4096, 2048, 2, 1, 256);
        // e3: K3 s2 p1, 256->512, Lout1024.
        conv2_k<3, 4, 2><<<dim3(1, 128, 8), 256, 0, stream>>>(
            h2q, e3w, e3b, h3q, nullptr, nullptr, nullptr,
            256, 2048, 1024, 1, 0, 512);

        // res block 0
        gnstats_k<<<dim3(64), 256, 0, stream>>>(h3q, r0g1g, r0g1b, scA, shA, 512, 1024, 8);
        conv2_k<3, 2, 1><<<dim3(2, 32, 8), 256, 0, stream>>>(
            h3q, r0c1w, nullptr, t2q, scA, shA, nullptr,
            512, 1024, 1024, 1, 0, 128);
        gnstats_k<<<dim3(64), 256, 0, stream>>>(t2q, r0g2g, r0g2b, scB, shB, 128, 1024, 8);
        conv2_k<1, 4, 1><<<dim3(1, 128, 8), 256, 0, stream>>>(
            t2q, r0c2w, nullptr, h3q, scB, shB, h3q,
            128, 1024, 1024, 0, 0, 512);

        // res block 1
        gnstats_k<<<dim3(64), 256, 0, stream>>>(h3q, r1g1g, r1g1b, scA, shA, 512, 1024, 8);
        conv2_k<3, 2, 1><<<dim3(2, 32, 8), 256, 0, stream>>>(
            h3q, r1c1w, nullptr, t2q, scA, shA, nullptr,
            512, 1024, 1024, 1, 0, 128);
        gnstats_k<<<dim3(64), 256, 0, stream>>>(t2q, r1g2g, r1g2b, scB, shB, 128, 1024, 8);
        conv2_k<1, 4, 1><<<dim3(1, 128, 8), 256, 0, stream>>>(
            t2q, r1c2w, nullptr, h3q, scB, shB, h3q,
            128, 1024, 1024, 0, 0, 512);

        // pre-VQ 1x1 conv -> z quarter (contiguous [pos,128])
        prevq_k<<<dim3(4, 32, 8), 256, 0, stream>>>(
            h3q, pvw, pvb, z + (size_t)q * 8192 * 128);
    }

    // ---- VQ: writes out_q (final fp32), hist, loss, indices ----
    vq_k<<<dim3(512), 256, 0, stream>>>(z, CB, out_q, lossA, hist, ipArr);

    // ---- behavior head ----
    pool_k<<<dim3(4096), 256, 0, stream>>>(out_q, zp);
    beh_k<<<dim3(1), 256, 0, stream>>>(zp, bh1w, bh1b, bh2w, bh2b, bh3w, bh3b, out_beh);

    // ---- decoder, per batch-quarter; t2-pair parity-split transpose convs ----
    for (int q = 0; q < 4; ++q) {
        convt3_k<3><<<dim3(2, 64, 8), 256, 0, stream>>>(
            out_q + (size_t)q * 1048576, d1w, d1b, d1o, 128, 1024, 512);
        convt3_k<5><<<dim3(4, 32, 8), 256, 0, stream>>>(
            d1o, d2w, d2b, d2o, 512, 2048, 256);
        conv2_k<7, 4, 1><<<dim3(4, 32, 8), 256, 0, stream>>>(
            d2o, d3w, d3b, out_xrec + (size_t)q * 4194304, nullptr, nullptr, nullptr,
            256, 4096, 4096, 3, 0, 128);
    }

    // ---- one-hot enc (overwrites enc-region scratch with the real output) ----
    enc_k<<<dim3(65536), 256, 0, stream>>>(ipArr, (float2*)out_enc);

    // ---- loss + perplexity ----
    fin_k<<<dim3(1), 1024, 0, stream>>>(hist, lossA, out_loss, out_perp);
}

// Round 4
// 6447.399 us; speedup vs baseline: 3.8366x; 2.6270x over previous
//
#include <hip/hip_runtime.h>

// All tensors fp32 (per the reference: inputs, weights, outputs all float32).

// ---------------------------------------------------------------------------
// LDS-tiled direct conv1d ("implicit GEMM"). Block = 64 co x 64 t for one b.
// Threads 256 = 16tx(t) x 16ty(co); each thread 4co x 4t register tile.
// Per ci-chunk (CI channels): stage input span (GN+ReLU fused here) and
// weights [ci][k][64co] in LDS, then FMA from aligned LDS vectors.
//   TSTORE: write transposed [pos][co] layout (pre-VQ z).
//   VSTORE: float4 stores (dst 16B-aligned); else scalar stores.
// ---------------------------------------------------------------------------
template<int K, int S, bool GN, bool RESID, bool RELU_OUT, bool TSTORE, bool VSTORE>
__global__ __launch_bounds__(256) void convtile_k(
    const float* __restrict__ in, const float* __restrict__ w,
    const float* __restrict__ bias, float* __restrict__ out,
    const float* __restrict__ scale, const float* __restrict__ shift,
    const float* __restrict__ resid,
    int Cin, int Lin, int Lout, int pad, int Cout)
{
    constexpr int CI    = (K == 1) ? 32 : 16;   // ci chunk
    constexpr int SPAN  = 63 * S + K;           // staged input span per ci
    constexpr int SPANP = (SPAN + 3) & ~3;      // 16B-aligned row stride
    constexpr int WN    = 3 * S + K;            // per-thread window

    __shared__ float lin[CI * SPANP];
    __shared__ float lw[CI * K * 64];

    const int tid = threadIdx.x;
    const int tx = tid & 15, ty = tid >> 4;
    const int t0 = blockIdx.x * 64;
    const int o0 = blockIdx.y * 64;
    const int b  = blockIdx.z;

    float acc[4][4];
    #pragma unroll
    for (int c = 0; c < 4; ++c) {
        float bv = bias ? bias[o0 + 4 * ty + c] : 0.0f;
        #pragma unroll
        for (int u = 0; u < 4; ++u) acc[c][u] = bv;
    }

    const float* inb = in + (size_t)b * Cin * Lin;
    const int p0 = t0 * S - pad;

    for (int ci0 = 0; ci0 < Cin; ci0 += CI) {
        __syncthreads();
        // ---- stage input (coalesced; GN+ReLU fused; zero-fill OOB) ----
        for (int idx = tid; idx < CI * SPAN; idx += 256) {
            int ci = idx / SPAN, j = idx - ci * SPAN;
            int p = p0 + j;
            bool ok = (p >= 0) && (p < Lin);
            float v = ok ? inb[(size_t)(ci0 + ci) * Lin + p] : 0.0f;
            if (GN) {
                float sc = scale[b * Cin + ci0 + ci];
                float sh = shift[b * Cin + ci0 + ci];
                v = ok ? fmaxf(v * sc + sh, 0.0f) : 0.0f;
            }
            lin[ci * SPANP + j] = v;
        }
        // ---- stage weights -> [ci][k][co64] (LDS writes conflict-free) ----
        for (int idx = tid; idx < CI * K * 64; idx += 256) {
            int co = idx & 63;
            int r  = idx >> 6;
            int k  = r % K, ci = r / K;
            lw[idx] = w[(size_t)(o0 + co) * Cin * K + (size_t)(ci0 + ci) * K + k];
        }
        __syncthreads();

        for (int ci = 0; ci < CI; ++ci) {
            float win[WN];
            const float* lrow = &lin[ci * SPANP + 4 * S * tx];
            #pragma unroll
            for (int j = 0; j < WN; ++j) win[j] = lrow[j];
            #pragma unroll
            for (int k = 0; k < K; ++k) {
                const float4 wv = *(const float4*)&lw[(ci * K + k) * 64 + 4 * ty];
                #pragma unroll
                for (int u = 0; u < 4; ++u) {
                    float x = win[u * S + k];
                    acc[0][u] += x * wv.x;
                    acc[1][u] += x * wv.y;
                    acc[2][u] += x * wv.z;
                    acc[3][u] += x * wv.w;
                }
            }
        }
    }

    // ---- epilogue ----
    if (RESID) {
        #pragma unroll
        for (int c = 0; c < 4; ++c) {
            const float4 rv = *(const float4*)(resid +
                ((size_t)b * Cout + o0 + 4 * ty + c) * Lout + t0 + 4 * tx);
            acc[c][0] += rv.x; acc[c][1] += rv.y; acc[c][2] += rv.z; acc[c][3] += rv.w;
        }
    }
    if (RELU_OUT) {
        #pragma unroll
        for (int c = 0; c < 4; ++c)
            #pragma unroll
            for (int u = 0; u < 4; ++u) acc[c][u] = fmaxf(acc[c][u], 0.f);
    }
    if (TSTORE) {
        // z[(b*L + t)*Cout + d], d = o0+4ty..+3
        #pragma unroll
        for (int u = 0; u < 4; ++u) {
            float4 v; v.x = acc[0][u]; v.y = acc[1][u]; v.z = acc[2][u]; v.w = acc[3][u];
            *(float4*)(out + ((size_t)b * Lout + t0 + 4 * tx + u) * Cout + o0 + 4 * ty) = v;
        }
    } else if (VSTORE) {
        #pragma unroll
        for (int c = 0; c < 4; ++c) {
            float4 v; v.x = acc[c][0]; v.y = acc[c][1]; v.z = acc[c][2]; v.w = acc[c][3];
            *(float4*)(out + ((size_t)b * Cout + o0 + 4 * ty + c) * Lout + t0 + 4 * tx) = v;
        }
    } else {
        #pragma unroll
        for (int c = 0; c < 4; ++c)
            #pragma unroll
            for (int u = 0; u < 4; ++u)
                out[((size_t)b * Cout + o0 + 4 * ty + c) * Lout + t0 + 4 * tx + u] = acc[c][u];
    }
}

// ---------------------------------------------------------------------------
// ConvTranspose1d stride-2, parity-split, t2-PAIR per thread: thread owns
// input indices (t2, t2+1) -> 4 consecutive outputs 2t2..2t2+3 for 8 output
// channels (32 accumulators). One float4 store per channel (dst 16B-aligned).
// ---------------------------------------------------------------------------
template<int K>
__global__ __launch_bounds__(256) void convt3_k(
    const float* __restrict__ in, const float* __restrict__ w,
    const float* __restrict__ bias, float* __restrict__ out,
    int Cin, int Lin, int Cout)
{
    constexpr int WN = (K == 5) ? 4 : 3;
    int t2 = (blockIdx.x * 256 + threadIdx.x) * 2;   // first of the pair
    if (t2 >= Lin) return;
    int o0 = blockIdx.y * 8;
    int b  = blockIdx.z;
    const int Lout = 2 * Lin;

    const float* inb = in + (size_t)b * Cin * Lin;
    const float* wb  = w + (size_t)o0 * Cin * K;
    const size_t ws  = (size_t)Cin * K;

    float acc[8][4];
    #pragma unroll
    for (int c = 0; c < 8; ++c) {
        float bv = bias[o0 + c];
        #pragma unroll
        for (int u = 0; u < 4; ++u) acc[c][u] = bv;
    }

    const int q0 = (K == 5) ? (t2 - 1) : t2;
    const bool fast = (q0 >= 0) && (q0 + WN <= Lin);

    for (int i = 0; i < Cin; ++i) {
        const float* xi = inb + (size_t)i * Lin;
        float win[WN];
        #pragma unroll
        for (int j = 0; j < WN; ++j) {
            int p = q0 + j;
            bool ok = fast || (p >= 0 && p < Lin);
            win[j] = ok ? xi[p] : 0.0f;
        }
        const float* wi = wb + (size_t)i * K;
        #pragma unroll
        for (int c = 0; c < 8; ++c) {
            const float* wc = wi + (size_t)c * ws;
            if constexpr (K == 5) {
                float w0 = wc[0], w1 = wc[1], w2 = wc[2], w3 = wc[3], w4 = wc[4];
                acc[c][0] += w0 * win[0] + w2 * win[1] + w4 * win[2];
                acc[c][1] += w1 * win[1] + w3 * win[2];
                acc[c][2] += w0 * win[1] + w2 * win[2] + w4 * win[3];
                acc[c][3] += w1 * win[2] + w3 * win[3];
            } else {
                float w0 = wc[0], w1 = wc[1], w2 = wc[2];
                acc[c][0] += w1 * win[0];
                acc[c][1] += w0 * win[0] + w2 * win[1];
                acc[c][2] += w1 * win[1];
                acc[c][3] += w0 * win[1] + w2 * win[2];
            }
        }
    }
    size_t base = ((size_t)b * Cout + o0) * (size_t)Lout + (size_t)(2 * t2);
    #pragma unroll
    for (int c = 0; c < 8; ++c) {
        float4 v;
        v.x = fmaxf(acc[c][0], 0.f);
        v.y = fmaxf(acc[c][1], 0.f);
        v.z = fmaxf(acc[c][2], 0.f);
        v.w = fmaxf(acc[c][3], 0.f);
        *(float4*)(out + base + (size_t)c * Lout) = v;
    }
}

// ---------------------------------------------------------------------------
// GroupNorm stats -> per-(b,c) scale/shift (eps 1e-5)
// ---------------------------------------------------------------------------
__global__ __launch_bounds__(256) void gnstats_k(
    const float* __restrict__ x, const float* __restrict__ g,
    const float* __restrict__ be, float* __restrict__ scale,
    float* __restrict__ shift, int C, int L, int G)
{
    int tid = threadIdx.x;
    int b = blockIdx.x / G, gr = blockIdx.x % G;
    int cpg = C / G;
    size_t n = (size_t)cpg * L;
    const float* base = x + ((size_t)b * C + (size_t)gr * cpg) * L;
    float s = 0.f, s2 = 0.f;
    for (size_t idx = tid; idx < n; idx += 256) { float v = base[idx]; s += v; s2 += v * v; }
    __shared__ float rs[256], rq[256];
    rs[tid] = s; rq[tid] = s2; __syncthreads();
    for (int off = 128; off > 0; off >>= 1) {
        if (tid < off) { rs[tid] += rs[tid + off]; rq[tid] += rq[tid + off]; }
        __syncthreads();
    }
    float mean = rs[0] / (float)n;
    float var  = rq[0] / (float)n - mean * mean;
    float inv  = rsqrtf(var + 1e-5f);
    if (tid < cpg) {
        int c = gr * cpg + tid;
        float ga = g[c], bb = be[c];
        scale[b * C + c] = inv * ga;
        shift[b * C + c] = bb - mean * inv * ga;
    }
}

// ---------------------------------------------------------------------------
// VQ: 64 positions/block, 16 code-tiles of 64, 4x4 register dot tiles.
// ---------------------------------------------------------------------------
__global__ __launch_bounds__(256) void vq_k(
    const float* __restrict__ z,       // [32768,128]
    const float* __restrict__ cb,      // [1024,128]
    float* __restrict__ out_q,         // [B,128,1024]
    float* __restrict__ lossAcc,
    unsigned int* __restrict__ hist,
    int* __restrict__ ip_out)
{
    const int tid = threadIdx.x;
    const int pbase = blockIdx.x * 64;
    __shared__ float zs[64 * 129];
    __shared__ float cbs[64 * 129];
    __shared__ float cn[64];
    __shared__ float rd[256];
    __shared__ int   ri[256];
    __shared__ int   ip[64];

    for (int f = tid; f < 64 * 128; f += 256) {
        int p = f >> 7, d = f & 127;
        zs[p * 129 + d] = z[(size_t)pbase * 128 + f];
    }

    float mind[4]; int minc[4];
    #pragma unroll
    for (int a = 0; a < 4; ++a) { mind[a] = 3.4e38f; minc[a] = 0; }
    const int tp = tid >> 4, tr = tid & 15;
    const int prow = tp * 4, crow = tr * 4;

    for (int ct = 0; ct < 16; ++ct) {
        __syncthreads();
        for (int f = tid; f < 64 * 128; f += 256) {
            int c = f >> 7, d = f & 127;
            cbs[c * 129 + d] = cb[((size_t)ct * 64 + c) * 128 + d];
        }
        __syncthreads();
        if (tid < 64) {
            float s = 0.f;
            for (int d = 0; d < 128; ++d) { float v = cbs[tid * 129 + d]; s += v * v; }
            cn[tid] = s;
        }
        __syncthreads();
        float dot[4][4];
        #pragma unroll
        for (int a = 0; a < 4; ++a)
            #pragma unroll
            for (int e = 0; e < 4; ++e) dot[a][e] = 0.f;
        for (int d = 0; d < 128; ++d) {
            float za[4], cc[4];
            #pragma unroll
            for (int a = 0; a < 4; ++a) za[a] = zs[(prow + a) * 129 + d];
            #pragma unroll
            for (int e = 0; e < 4; ++e) cc[e] = cbs[(crow + e) * 129 + d];
            #pragma unroll
            for (int a = 0; a < 4; ++a)
                #pragma unroll
                for (int e = 0; e < 4; ++e) dot[a][e] += za[a] * cc[e];
        }
        #pragma unroll
        for (int e = 0; e < 4; ++e) {
            int c = ct * 64 + crow + e;
            float cne = cn[crow + e];
            #pragma unroll
            for (int a = 0; a < 4; ++a) {
                float dist = cne - 2.0f * dot[a][e];
                if (dist < mind[a]) { mind[a] = dist; minc[a] = c; }
            }
        }
    }

    for (int a = 0; a < 4; ++a) {
        __syncthreads();
        rd[tid] = mind[a]; ri[tid] = minc[a];
        __syncthreads();
        if (tr == 0) {
            float bd = rd[tid]; int bi = ri[tid];
            for (int u = 1; u < 16; ++u) {
                float dv = rd[tid + u]; int iv = ri[tid + u];
                if (dv < bd || (dv == bd && iv < bi)) { bd = dv; bi = iv; }
            }
            ip[prow + a] = bi;
            atomicAdd(&hist[bi], 1u);
        }
    }
    __syncthreads();

    if (tid < 64) ip_out[pbase + tid] = ip[tid];

    float lp = 0.f;
    for (int f = tid; f < 64 * 128; f += 256) {
        int p = f >> 7, d = f & 127;
        int gp = pbase + p, b = gp >> 10, l = gp & 1023;
        float qv = cb[(size_t)ip[p] * 128 + d];
        float zv = zs[p * 129 + d];
        float df = qv - zv; lp += df * df;
        out_q[(((size_t)b * 128 + d) << 10) + l] = qv;
    }
    rd[tid] = lp; __syncthreads();
    for (int off = 128; off > 0; off >>= 1) {
        if (tid < off) rd[tid] += rd[tid + off];
        __syncthreads();
    }
    if (tid == 0) atomicAdd(lossAcc, rd[0]);
}

// one-hot enc write (fp32) from indices; enc region was scratch until now.
__global__ __launch_bounds__(256) void enc_k(
    const int* __restrict__ ip, float2* __restrict__ enc)
{
    size_t idx = (size_t)blockIdx.x * 256 + threadIdx.x;   // 16,777,216 float2
    int p  = (int)(idx >> 9);
    int q2 = (int)(idx & 511);
    int best = ip[p];
    int c0 = q2 * 2;
    float2 v;
    v.x = (c0     == best) ? 1.0f : 0.0f;
    v.y = (c0 + 1 == best) ? 1.0f : 0.0f;
    enc[idx] = v;
}

// mean over L=1024 of fp32 [B,D,L]; one block per (b,d)
__global__ __launch_bounds__(256) void pool_k(const float* __restrict__ q, float* __restrict__ zp)
{
    int tid = threadIdx.x;
    const float* row = q + (size_t)blockIdx.x * 1024;
    float s = 0.f;
    for (int l = tid; l < 1024; l += 256) s += row[l];
    __shared__ float rs[256];
    rs[tid] = s; __syncthreads();
    for (int off = 128; off > 0; off >>= 1) {
        if (tid < off) rs[tid] += rs[tid + off];
        __syncthreads();
    }
    if (tid == 0) zp[blockIdx.x] = rs[0] * (1.0f / 1024.0f);
}

// behavior MLP head, single block
__global__ __launch_bounds__(256) void beh_k(
    const float* __restrict__ zp,
    const float* __restrict__ w1, const float* __restrict__ b1,
    const float* __restrict__ w2, const float* __restrict__ b2,
    const float* __restrict__ w3, const float* __restrict__ b3,
    float* __restrict__ out)
{
    __shared__ float zs[32 * 128];
    __shared__ float h1s[32 * 128];
    __shared__ float h2s[32 * 64];
    int tid = threadIdx.x;
    for (int f = tid; f < 4096; f += 256) zs[f] = zp[f];
    __syncthreads();
    for (int f = tid; f < 4096; f += 256) {
        int bi = f >> 7, j = f & 127;
        float acc = b1[j];
        for (int d = 0; d < 128; ++d) acc += zs[bi * 128 + d] * w1[j * 128 + d];
        h1s[f] = fmaxf(acc, 0.f);
    }
    __syncthreads();
    for (int f = tid; f < 2048; f += 256) {
        int bi = f >> 6, j = f & 63;
        float acc = b2[j];
        for (int d = 0; d < 128; ++d) acc += h1s[bi * 128 + d] * w2[j * 128 + d];
        h2s[f] = fmaxf(acc, 0.f);
    }
    __syncthreads();
    if (tid < 128) {
        int bi = tid >> 2, j = tid & 3;
        float acc = b3[j];
        for (int d = 0; d < 64; ++d) acc += h2s[bi * 64 + d] * w3[j * 64 + d];
        out[tid] = acc;
    }
}

__global__ __launch_bounds__(1024) void init_k(unsigned int* hist, float* lossAcc)
{
    hist[threadIdx.x] = 0u;
    if (threadIdx.x == 0) *lossAcc = 0.f;
}

__global__ __launch_bounds__(1024) void fin_k(
    const unsigned int* __restrict__ hist, const float* __restrict__ lossAcc,
    float* __restrict__ out_loss, float* __restrict__ out_perp)
{
    __shared__ float rs[1024];
    int tid = threadIdx.x;
    float avg = (float)hist[tid] * (1.0f / 32768.0f);
    rs[tid] = avg * logf(avg + 1e-10f);
    __syncthreads();
    for (int off = 512; off > 0; off >>= 1) {
        if (tid < off) rs[tid] += rs[tid + off];
        __syncthreads();
    }
    if (tid == 0) {
        out_perp[0] = expf(-rs[0]);
        out_loss[0] = 0.25f * lossAcc[0] * (1.0f / 4194304.0f);
    }
}

// ---------------------------------------------------------------------------
extern "C" void kernel_launch(void* const* d_in, const int* in_sizes, int n_in,
                              void* d_out, int out_size, void* d_ws, size_t ws_size,
                              hipStream_t stream)
{
    const float* X    = (const float*)d_in[0];
    const float* e1w  = (const float*)d_in[1];  const float* e1b = (const float*)d_in[2];
    const float* e2w  = (const float*)d_in[3];  const float* e2b = (const float*)d_in[4];
    const float* e3w  = (const float*)d_in[5];  const float* e3b = (const float*)d_in[6];
    const float* r0g1g = (const float*)d_in[7];  const float* r0g1b = (const float*)d_in[8];
    const float* r0c1w = (const float*)d_in[9];
    const float* r0g2g = (const float*)d_in[10]; const float* r0g2b = (const float*)d_in[11];
    const float* r0c2w = (const float*)d_in[12];
    const float* r1g1g = (const float*)d_in[13]; const float* r1g1b = (const float*)d_in[14];
    const float* r1c1w = (const float*)d_in[15];
    const float* r1g2g = (const float*)d_in[16]; const float* r1g2b = (const float*)d_in[17];
    const float* r1c2w = (const float*)d_in[18];
    const float* pvw  = (const float*)d_in[19]; const float* pvb = (const float*)d_in[20];
    const float* CB   = (const float*)d_in[21];
    const float* d1w  = (const float*)d_in[22]; const float* d1b = (const float*)d_in[23];
    const float* d2w  = (const float*)d_in[24]; const float* d2b = (const float*)d_in[25];
    const float* d3w  = (const float*)d_in[26]; const float* d3b = (const float*)d_in[27];
    const float* bh1w = (const float*)d_in[28]; const float* bh1b = (const float*)d_in[29];
    const float* bh2w = (const float*)d_in[30]; const float* bh2b = (const float*)d_in[31];
    const float* bh3w = (const float*)d_in[32]; const float* bh3b = (const float*)d_in[33];

    // ---- output regions (fp32 elements) ----
    float* out = (float*)d_out;
    const size_t N_XREC = 16777216ull, N_Q = 4194304ull, N_ENC = 33554432ull;
    float* out_loss = out;
    float* out_xrec = out + 1;                          // 64 MiB region
    float* out_perp = out + 1 + N_XREC;
    float* out_q    = out + 2 + N_XREC;                 // 16 MiB region
    float* out_enc  = out + 2 + N_XREC + N_Q;           // 128 MiB region
    float* out_beh  = out + 2 + N_XREC + N_Q + N_ENC;

    // ---- scratch staging (serial lifetimes; FULL-B encoder, HALF-B decoder) ----
    // xrec region: h1 (e1 out, 32x128x4096 = 16,777,216 fl) at out+4 (16B-aligned).
    //   Overruns region by 3 floats into {out_perp, out_q[0..1]} - all rewritten
    //   later by vq_k / fin_k. h3 (32x512x1024, same size) aliases h1 (e3 reads
    //   only h2). c2 writes h3 in-place over its own resid read (elementwise).
    float* h1 = out + 4;
    float* h3 = h1;
    // enc region (33,554,432 fl), base A = out_enc+2 (16B-aligned):
    //   encoder phase: h2 [0,16.8M) ; t2q [16.8M,21.0M) ; z [21.0M,25.2M)
    //   decoder phase: d1o [0,16.8M) ; d2o [16.8M,33.6M) (+2 fl into out_beh,
    //   which beh_k writes afterwards). enc_k finally overwrites whole region.
    float* A   = out_enc + 2;
    float* h2  = A;
    float* t2q = A + 16777216;
    float* z   = A + 20971520;
    float* d1o = A;
    float* d2o = A + 16777216;

    // ---- d_ws: smalls ONLY (~320 KB) ----
    float* W = (float*)d_ws;
    float* lossA = W;                              // 1 (+pad 16)
    unsigned int* hist = (unsigned int*)(W + 16);  // 1,024
    float* zp   = W + 16 + 1024;                   // 4,096
    int* ipArr  = (int*)(W + 16 + 1024 + 4096);    // 32,768
    float* scA  = W + 16 + 1024 + 4096 + 32768;    // 16,384 (32 b x 512)
    float* shA  = scA + 16384;                     // 16,384
    float* scB  = shA + 16384;                     // 4,096 (32 b x 128)
    float* shB  = scB + 4096;                      // 4,096

    init_k<<<dim3(1), dim3(1024), 0, stream>>>(hist, lossA);

    // ---- encoder (full batch B=32) ----
    // e1: K7 s1 p3, 128->128, L4096
    convtile_k<7,1,false,false,true,false,true><<<dim3(64, 2, 32), 256, 0, stream>>>(
        X, e1w, e1b, h1, nullptr, nullptr, nullptr, 128, 4096, 4096, 3, 128);
    // e2: K5 s2 p2, 128->256, L4096->2048
    convtile_k<5,2,false,false,true,false,true><<<dim3(32, 4, 32), 256, 0, stream>>>(
        h1, e2w, e2b, h2, nullptr, nullptr, nullptr, 128, 4096, 2048, 2, 256);
    // e3: K3 s2 p1, 256->512, 2048->1024 (writes h3, aliasing h1; reads only h2)
    convtile_k<3,2,false,false,false,false,true><<<dim3(16, 8, 32), 256, 0, stream>>>(
        h2, e3w, e3b, h3, nullptr, nullptr, nullptr, 256, 2048, 1024, 1, 512);

    // res block 0
    gnstats_k<<<dim3(256), 256, 0, stream>>>(h3, r0g1g, r0g1b, scA, shA, 512, 1024, 8);
    convtile_k<3,1,true,false,false,false,true><<<dim3(16, 2, 32), 256, 0, stream>>>(
        h3, r0c1w, nullptr, t2q, scA, shA, nullptr, 512, 1024, 1024, 1, 128);
    gnstats_k<<<dim3(256), 256, 0, stream>>>(t2q, r0g2g, r0g2b, scB, shB, 128, 1024, 8);
    convtile_k<1,1,true,true,false,false,true><<<dim3(16, 8, 32), 256, 0, stream>>>(
        t2q, r0c2w, nullptr, h3, scB, shB, h3, 128, 1024, 1024, 0, 512);

    // res block 1
    gnstats_k<<<dim3(256), 256, 0, stream>>>(h3, r1g1g, r1g1b, scA, shA, 512, 1024, 8);
    convtile_k<3,1,true,false,false,false,true><<<dim3(16, 2, 32), 256, 0, stream>>>(
        h3, r1c1w, nullptr, t2q, scA, shA, nullptr, 512, 1024, 1024, 1, 128);
    gnstats_k<<<dim3(256), 256, 0, stream>>>(t2q, r1g2g, r1g2b, scB, shB, 128, 1024, 8);
    convtile_k<1,1,true,true,false,false,true><<<dim3(16, 8, 32), 256, 0, stream>>>(
        t2q, r1c2w, nullptr, h3, scB, shB, h3, 128, 1024, 1024, 0, 512);

    // pre-VQ 1x1 conv 512->128, transposed store -> z [pos,128]
    convtile_k<1,1,false,false,false,true,true><<<dim3(16, 2, 32), 256, 0, stream>>>(
        h3, pvw, pvb, z, nullptr, nullptr, nullptr, 512, 1024, 1024, 0, 128);

    // ---- VQ: writes out_q (final fp32), hist, loss, indices ----
    vq_k<<<dim3(512), 256, 0, stream>>>(z, CB, out_q, lossA, hist, ipArr);

    // ---- decoder, per batch-HALF (16 samples) ----
    for (int h = 0; h < 2; ++h) {
        convt3_k<3><<<dim3(2, 64, 16), 256, 0, stream>>>(
            out_q + (size_t)h * 2097152, d1w, d1b, d1o, 128, 1024, 512);
        convt3_k<5><<<dim3(4, 32, 16), 256, 0, stream>>>(
            d1o, d2w, d2b, d2o, 512, 2048, 256);
        convtile_k<7,1,false,false,false,false,false><<<dim3(64, 2, 16), 256, 0, stream>>>(
            d2o, d3w, d3b, out_xrec + (size_t)h * 8388608, nullptr, nullptr, nullptr,
            256, 4096, 4096, 3, 128);
    }

    // ---- behavior head (after decoder: d2o overhangs 2 floats into out_beh) ----
    pool_k<<<dim3(4096), 256, 0, stream>>>(out_q, zp);
    beh_k<<<dim3(1), 256, 0, stream>>>(zp, bh1w, bh1b, bh2w, bh2b, bh3w, bh3b, out_beh);

    // ---- one-hot enc (overwrites enc-region scratch with the real output) ----
    enc_k<<<dim3(65536), 256, 0, stream>>>(ipArr, (float2*)out_enc);

    // ---- loss + perplexity ----
    fin_k<<<dim3(1), 1024, 0, stream>>>(hist, lossA, out_loss, out_perp);
}